// Round 1
// baseline (2710.347 us; speedup 1.0000x reference)
//
#include <hip/hip_runtime.h>
#include <hip/hip_bf16.h>
#include <math.h>

#define D_MODEL 1024
#define D_INNER 2048
#define DT_RANK 64
#define D_STATE 16
#define BSZ 2
#define SEQ 2048
#define NROW (BSZ * SEQ)   // 4096

// ---------------- LayerNorm (one block per row, D_MODEL=1024, 256 thr x float4) ----
__global__ __launch_bounds__(256) void ln_kernel(const float* __restrict__ x,
                                                 const float* __restrict__ w,
                                                 const float* __restrict__ b,
                                                 float* __restrict__ xn) {
    int row = blockIdx.x;
    int tid = threadIdx.x;
    const float4* xr = (const float4*)(x + (size_t)row * D_MODEL);
    float4 v = xr[tid];
    float s  = v.x + v.y + v.z + v.w;
    float ss = v.x * v.x + v.y * v.y + v.z * v.z + v.w * v.w;
#pragma unroll
    for (int o = 32; o > 0; o >>= 1) {
        s  += __shfl_down(s, o);
        ss += __shfl_down(ss, o);
    }
    __shared__ float red[8];
    int wid = tid >> 6, lane = tid & 63;
    if (lane == 0) { red[wid] = s; red[4 + wid] = ss; }
    __syncthreads();
    s  = red[0] + red[1] + red[2] + red[3];
    ss = red[4] + red[5] + red[6] + red[7];
    float mu  = s * (1.0f / D_MODEL);
    float var = ss * (1.0f / D_MODEL) - mu * mu;
    float inv = rsqrtf(var + 1e-5f);
    float4 wv = ((const float4*)w)[tid];
    float4 bv = ((const float4*)b)[tid];
    float4 o4;
    o4.x = (v.x - mu) * inv * wv.x + bv.x;
    o4.y = (v.y - mu) * inv * wv.y + bv.y;
    o4.z = (v.z - mu) * inv * wv.z + bv.z;
    o4.w = (v.w - mu) * inv * wv.w + bv.w;
    ((float4*)(xn + (size_t)row * D_MODEL))[tid] = o4;
}

// ---------------- Generic tiled GEMM: C[M,N] = A[M,K] * B[N,K]^T ----------------
// MODE 0: split-store: col<splitN -> C (ld=ldc), else C1 (ld=ldc, col-splitN)
// MODE 1: C = softplus(acc + extra[col])
// MODE 2: C = acc + extra[row*ldc+col]   (residual)
// MODE 3: plain store
#define BM 64
#define BN 64
#define BK 16

template <int MODE>
__global__ __launch_bounds__(256) void gemm_tn(const float* __restrict__ A, int lda,
                                               const float* __restrict__ B, int ldb,
                                               float* __restrict__ C, int ldc,
                                               int M, int N, int K,
                                               const float* __restrict__ extra,
                                               float* __restrict__ C1, int splitN) {
    __shared__ float As[BK][BM];
    __shared__ float Bs[BK][BN];
    int bm = blockIdx.y * BM, bn = blockIdx.x * BN;
    int tid = threadIdx.x;
    int tx = tid & 15, ty = tid >> 4;
    int lrow = tid >> 2, lseg = (tid & 3) << 2;   // tile-load coords
    float acc[4][4] = {};

    for (int k0 = 0; k0 < K; k0 += BK) {
        float4 av = make_float4(0.f, 0.f, 0.f, 0.f);
        float4 bv = make_float4(0.f, 0.f, 0.f, 0.f);
        int agr = bm + lrow;
        if (agr < M) av = *(const float4*)(A + (size_t)agr * lda + k0 + lseg);
        int bgr = bn + lrow;
        if (bgr < N) bv = *(const float4*)(B + (size_t)bgr * ldb + k0 + lseg);
        __syncthreads();   // previous iter finished reading LDS
        As[lseg + 0][lrow] = av.x; As[lseg + 1][lrow] = av.y;
        As[lseg + 2][lrow] = av.z; As[lseg + 3][lrow] = av.w;
        Bs[lseg + 0][lrow] = bv.x; Bs[lseg + 1][lrow] = bv.y;
        Bs[lseg + 2][lrow] = bv.z; Bs[lseg + 3][lrow] = bv.w;
        __syncthreads();
#pragma unroll
        for (int k = 0; k < BK; ++k) {
            float4 a4 = *(const float4*)&As[k][ty << 2];
            float4 b4 = *(const float4*)&Bs[k][tx << 2];
            float ar[4] = {a4.x, a4.y, a4.z, a4.w};
            float br[4] = {b4.x, b4.y, b4.z, b4.w};
#pragma unroll
            for (int i = 0; i < 4; ++i)
#pragma unroll
                for (int j = 0; j < 4; ++j) acc[i][j] += ar[i] * br[j];
        }
    }

#pragma unroll
    for (int i = 0; i < 4; ++i) {
        int gr = bm + (ty << 2) + i;
        if (gr >= M) continue;
#pragma unroll
        for (int j = 0; j < 4; ++j) {
            int gc = bn + (tx << 2) + j;
            if (gc >= N) continue;
            float v = acc[i][j];
            if (MODE == 0) {
                if (gc < splitN) C[(size_t)gr * ldc + gc] = v;
                else             C1[(size_t)gr * ldc + (gc - splitN)] = v;
            } else if (MODE == 1) {
                v += extra[gc];
                v = (v > 20.f) ? v : log1pf(expf(v));
                C[(size_t)gr * ldc + gc] = v;
            } else if (MODE == 2) {
                C[(size_t)gr * ldc + gc] = v + extra[(size_t)gr * ldc + gc];
            } else {
                C[(size_t)gr * ldc + gc] = v;
            }
        }
    }
}

// ---------------- causal depthwise conv1d (k=4, left pad 3) + SiLU ----------------
__global__ __launch_bounds__(256) void conv_silu(const float* __restrict__ xin,
                                                 const float* __restrict__ w,
                                                 const float* __restrict__ cb,
                                                 float* __restrict__ xc) {
    int idx = blockIdx.x * 256 + threadIdx.x;          // over 4096 * 512 d4-groups
    int d4 = idx & 511;
    int m  = idx >> 9;
    int l  = m & (SEQ - 1);
    int d  = d4 << 2;
    float4 w0 = ((const float4*)w)[d + 0];
    float4 w1 = ((const float4*)w)[d + 1];
    float4 w2 = ((const float4*)w)[d + 2];
    float4 w3 = ((const float4*)w)[d + 3];
    float wr0[4] = {w0.x, w0.y, w0.z, w0.w};
    float wr1[4] = {w1.x, w1.y, w1.z, w1.w};
    float wr2[4] = {w2.x, w2.y, w2.z, w2.w};
    float wr3[4] = {w3.x, w3.y, w3.z, w3.w};
    float ax = cb[d], ay = cb[d + 1], az = cb[d + 2], aw = cb[d + 3];
#pragma unroll
    for (int j = 0; j < 4; ++j) {
        if (l - 3 + j >= 0) {
            float4 xv = *(const float4*)(xin + (size_t)(m - 3 + j) * D_INNER + d);
            ax += wr0[j] * xv.x;
            ay += wr1[j] * xv.y;
            az += wr2[j] * xv.z;
            aw += wr3[j] * xv.w;
        }
    }
    float4 o;
    o.x = ax / (1.f + expf(-ax));
    o.y = ay / (1.f + expf(-ay));
    o.z = az / (1.f + expf(-az));
    o.w = aw / (1.f + expf(-aw));
    *(float4*)(xc + (size_t)m * D_INNER + d) = o;
}

// ---------------- selective scan: one lane per (channel, state) -------------------
__global__ __launch_bounds__(256) void scan_kernel(const float* __restrict__ delta,
                                                   const float* __restrict__ xc,
                                                   const float* __restrict__ dbl,
                                                   const float* __restrict__ z,
                                                   const float* __restrict__ A_log,
                                                   const float* __restrict__ Dp,
                                                   float* __restrict__ y) {
    int g = blockIdx.x * 256 + threadIdx.x;   // 65536 total
    int n = g & 15;
    int c = g >> 4;                            // channel 0..4095
    int d = c & (D_INNER - 1);
    int b = c >> 11;
    float Acoef = -expf(A_log[d * D_STATE + n]);
    float Dv = Dp[d];
    float h = 0.f;
    size_t rowbase = (size_t)b * SEQ;
    for (int t = 0; t < SEQ; ++t) {
        size_t m = rowbase + t;
        float dt = delta[m * D_INNER + d];
        float u  = xc[m * D_INNER + d];
        float Bt = dbl[m * 96 + DT_RANK + n];
        float Ct = dbl[m * 96 + DT_RANK + D_STATE + n];
        float dA = expf(dt * Acoef);
        h = dA * h + (dt * u) * Bt;
        float p = h * Ct;
        p += __shfl_xor(p, 1, 16);
        p += __shfl_xor(p, 2, 16);
        p += __shfl_xor(p, 4, 16);
        p += __shfl_xor(p, 8, 16);
        if (n == 0) {
            float zv = z[m * D_INNER + d];
            float sz = zv / (1.f + expf(-zv));
            y[m * D_INNER + d] = (p + u * Dv) * sz;
        }
    }
}

extern "C" void kernel_launch(void* const* d_in, const int* in_sizes, int n_in,
                              void* d_out, int out_size, void* d_ws, size_t ws_size,
                              hipStream_t stream) {
    const float* x       = (const float*)d_in[0];
    const float* ln_w    = (const float*)d_in[1];
    const float* ln_b    = (const float*)d_in[2];
    const float* in_proj = (const float*)d_in[3];
    const float* conv_w  = (const float*)d_in[4];
    const float* conv_b  = (const float*)d_in[5];
    const float* x_proj  = (const float*)d_in[6];
    const float* dt_w    = (const float*)d_in[7];
    const float* dt_b    = (const float*)d_in[8];
    const float* A_log   = (const float*)d_in[9];
    const float* Dp      = (const float*)d_in[10];
    const float* out_w   = (const float*)d_in[11];
    float* out = (float*)d_out;

    char* ws = (char*)d_ws;
    const size_t MB = 1024ull * 1024ull;
    float* xn    = (float*)(ws);             // 16 MB  [4096,1024]
    float* x_in  = (float*)(ws + 16 * MB);   // 32 MB  [4096,2048]
    float* zbuf  = (float*)(ws + 48 * MB);   // 32 MB  [4096,2048]
    float* xc    = (float*)(ws + 80 * MB);   // 32 MB  [4096,2048]
    float* dbl   = (float*)(ws + 112 * MB);  // 1.5 MB [4096,96]
    float* delta = (float*)(ws + 114 * MB);  // 32 MB  [4096,2048]
    float* y     = x_in;                     // reuse: x_in dead after conv

    // 1. LayerNorm
    ln_kernel<<<NROW, 256, 0, stream>>>(x, ln_w, ln_b, xn);

    // 2. xz = xn @ in_proj^T  -> x_in | z
    gemm_tn<0><<<dim3(4096 / BN, NROW / BM), 256, 0, stream>>>(
        xn, D_MODEL, in_proj, D_MODEL, x_in, D_INNER, NROW, 2 * D_INNER, D_MODEL,
        nullptr, zbuf, D_INNER);

    // 3. causal depthwise conv + SiLU -> xc
    conv_silu<<<(NROW * (D_INNER / 4)) / 256, 256, 0, stream>>>(x_in, conv_w, conv_b, xc);

    // 4. dbl = xc @ x_proj^T   [4096, 96]
    gemm_tn<3><<<dim3((96 + BN - 1) / BN, NROW / BM), 256, 0, stream>>>(
        xc, D_INNER, x_proj, D_INNER, dbl, 96, NROW, 96, D_INNER,
        nullptr, nullptr, 0);

    // 5. delta = softplus(dt @ dt_proj^T + dt_b)   [4096, 2048]
    gemm_tn<1><<<dim3(D_INNER / BN, NROW / BM), 256, 0, stream>>>(
        dbl, 96, dt_w, DT_RANK, delta, D_INNER, NROW, D_INNER, DT_RANK,
        dt_b, nullptr, 0);

    // 6. selective scan (+ skip & gate fused)
    scan_kernel<<<(NROW * D_STATE * BSZ * 0 + 65536) / 256, 256, 0, stream>>>(
        delta, xc, dbl, zbuf, A_log, Dp, y);

    // 7. out = y @ out_proj^T + x
    gemm_tn<2><<<dim3(D_MODEL / BN, NROW / BM), 256, 0, stream>>>(
        y, D_INNER, out_w, D_INNER, out, D_MODEL, NROW, D_MODEL, D_INNER,
        x, nullptr, 0);
}

// Round 2
// 1318.610 us; speedup vs baseline: 2.0555x; 2.0555x over previous
//
#include <hip/hip_runtime.h>
#include <hip/hip_bf16.h>
#include <math.h>

#define D_MODEL 1024
#define D_INNER 2048
#define DT_RANK 64
#define D_STATE 16
#define BSZ 2
#define SEQ 2048
#define NROW (BSZ * SEQ)   // 4096
#define NC 8               // scan time-chunks
#define CL (SEQ / NC)      // 256 steps per chunk
#define NCH (BSZ * D_INNER) // 4096 scan channels

// ---------------- LayerNorm (one block per row, D_MODEL=1024, 256 thr x float4) ----
__global__ __launch_bounds__(256) void ln_kernel(const float* __restrict__ x,
                                                 const float* __restrict__ w,
                                                 const float* __restrict__ b,
                                                 float* __restrict__ xn) {
    int row = blockIdx.x;
    int tid = threadIdx.x;
    const float4* xr = (const float4*)(x + (size_t)row * D_MODEL);
    float4 v = xr[tid];
    float s  = v.x + v.y + v.z + v.w;
    float ss = v.x * v.x + v.y * v.y + v.z * v.z + v.w * v.w;
#pragma unroll
    for (int o = 32; o > 0; o >>= 1) {
        s  += __shfl_down(s, o);
        ss += __shfl_down(ss, o);
    }
    __shared__ float red[8];
    int wid = tid >> 6, lane = tid & 63;
    if (lane == 0) { red[wid] = s; red[4 + wid] = ss; }
    __syncthreads();
    s  = red[0] + red[1] + red[2] + red[3];
    ss = red[4] + red[5] + red[6] + red[7];
    float mu  = s * (1.0f / D_MODEL);
    float var = ss * (1.0f / D_MODEL) - mu * mu;
    float inv = rsqrtf(var + 1e-5f);
    float4 wv = ((const float4*)w)[tid];
    float4 bv = ((const float4*)b)[tid];
    float4 o4;
    o4.x = (v.x - mu) * inv * wv.x + bv.x;
    o4.y = (v.y - mu) * inv * wv.y + bv.y;
    o4.z = (v.z - mu) * inv * wv.z + bv.z;
    o4.w = (v.w - mu) * inv * wv.w + bv.w;
    ((float4*)(xn + (size_t)row * D_MODEL))[tid] = o4;
}

// ---------------- Generic tiled GEMM: C[M,N] = A[M,K] * B[N,K]^T ----------------
#define BM 64
#define BN 64
#define BK 16

template <int MODE>
__global__ __launch_bounds__(256) void gemm_tn(const float* __restrict__ A, int lda,
                                               const float* __restrict__ B, int ldb,
                                               float* __restrict__ C, int ldc,
                                               int M, int N, int K,
                                               const float* __restrict__ extra,
                                               float* __restrict__ C1, int splitN) {
    __shared__ float As[BK][BM];
    __shared__ float Bs[BK][BN];
    int bm = blockIdx.y * BM, bn = blockIdx.x * BN;
    int tid = threadIdx.x;
    int tx = tid & 15, ty = tid >> 4;
    int lrow = tid >> 2, lseg = (tid & 3) << 2;   // tile-load coords
    float acc[4][4] = {};

    for (int k0 = 0; k0 < K; k0 += BK) {
        float4 av = make_float4(0.f, 0.f, 0.f, 0.f);
        float4 bv = make_float4(0.f, 0.f, 0.f, 0.f);
        int agr = bm + lrow;
        if (agr < M) av = *(const float4*)(A + (size_t)agr * lda + k0 + lseg);
        int bgr = bn + lrow;
        if (bgr < N) bv = *(const float4*)(B + (size_t)bgr * ldb + k0 + lseg);
        __syncthreads();   // previous iter finished reading LDS
        As[lseg + 0][lrow] = av.x; As[lseg + 1][lrow] = av.y;
        As[lseg + 2][lrow] = av.z; As[lseg + 3][lrow] = av.w;
        Bs[lseg + 0][lrow] = bv.x; Bs[lseg + 1][lrow] = bv.y;
        Bs[lseg + 2][lrow] = bv.z; Bs[lseg + 3][lrow] = bv.w;
        __syncthreads();
#pragma unroll
        for (int k = 0; k < BK; ++k) {
            float4 a4 = *(const float4*)&As[k][ty << 2];
            float4 b4 = *(const float4*)&Bs[k][tx << 2];
            float ar[4] = {a4.x, a4.y, a4.z, a4.w};
            float br[4] = {b4.x, b4.y, b4.z, b4.w};
#pragma unroll
            for (int i = 0; i < 4; ++i)
#pragma unroll
                for (int j = 0; j < 4; ++j) acc[i][j] += ar[i] * br[j];
        }
    }

#pragma unroll
    for (int i = 0; i < 4; ++i) {
        int gr = bm + (ty << 2) + i;
        if (gr >= M) continue;
#pragma unroll
        for (int j = 0; j < 4; ++j) {
            int gc = bn + (tx << 2) + j;
            if (gc >= N) continue;
            float v = acc[i][j];
            if (MODE == 0) {
                if (gc < splitN) C[(size_t)gr * ldc + gc] = v;
                else             C1[(size_t)gr * ldc + (gc - splitN)] = v;
            } else if (MODE == 1) {
                v += extra[gc];
                v = (v > 20.f) ? v : log1pf(expf(v));
                C[(size_t)gr * ldc + gc] = v;
            } else if (MODE == 2) {
                C[(size_t)gr * ldc + gc] = v + extra[(size_t)gr * ldc + gc];
            } else {
                C[(size_t)gr * ldc + gc] = v;
            }
        }
    }
}

// ---------------- causal depthwise conv1d (k=4, left pad 3) + SiLU ----------------
__global__ __launch_bounds__(256) void conv_silu(const float* __restrict__ xin,
                                                 const float* __restrict__ w,
                                                 const float* __restrict__ cb,
                                                 float* __restrict__ xc) {
    int idx = blockIdx.x * 256 + threadIdx.x;          // over 4096 * 512 d4-groups
    int d4 = idx & 511;
    int m  = idx >> 9;
    int l  = m & (SEQ - 1);
    int d  = d4 << 2;
    float4 w0 = ((const float4*)w)[d + 0];
    float4 w1 = ((const float4*)w)[d + 1];
    float4 w2 = ((const float4*)w)[d + 2];
    float4 w3 = ((const float4*)w)[d + 3];
    float wr0[4] = {w0.x, w0.y, w0.z, w0.w};
    float wr1[4] = {w1.x, w1.y, w1.z, w1.w};
    float wr2[4] = {w2.x, w2.y, w2.z, w2.w};
    float wr3[4] = {w3.x, w3.y, w3.z, w3.w};
    float ax = cb[d], ay = cb[d + 1], az = cb[d + 2], aw = cb[d + 3];
#pragma unroll
    for (int j = 0; j < 4; ++j) {
        if (l - 3 + j >= 0) {
            float4 xv = *(const float4*)(xin + (size_t)(m - 3 + j) * D_INNER + d);
            ax += wr0[j] * xv.x;
            ay += wr1[j] * xv.y;
            az += wr2[j] * xv.z;
            aw += wr3[j] * xv.w;
        }
    }
    float4 o;
    o.x = ax / (1.f + expf(-ax));
    o.y = ay / (1.f + expf(-ay));
    o.z = az / (1.f + expf(-az));
    o.w = aw / (1.f + expf(-aw));
    *(float4*)(xc + (size_t)m * D_INNER + d) = o;
}

// ---------------- chunked selective scan ------------------------------------------
// Phase 1: per (chunk k, channel c, state n) compute chunk transfer:
//   P = prod_t a[t],  S = scan end value starting from h=0
__global__ __launch_bounds__(256) void scan_phase1(const float* __restrict__ delta,
                                                   const float* __restrict__ xc,
                                                   const float* __restrict__ dbl,
                                                   const float* __restrict__ A_log,
                                                   float* __restrict__ Pout,
                                                   float* __restrict__ Sout) {
    int g = blockIdx.x * 256 + threadIdx.x;   // NCH * NC * 16 = 524288
    int n  = g & 15;
    int gc = g >> 4;               // [0, NCH*NC)
    int c  = gc & (NCH - 1);       // channel: consecutive groups -> consecutive channels
    int k  = gc >> 12;             // chunk id (NCH = 4096 = 2^12)
    int d  = c & (D_INNER - 1);
    int b  = c >> 11;
    float Acoef = -expf(A_log[d * D_STATE + n]);
    float P = 1.f, h = 0.f;
    size_t rowbase = (size_t)b * SEQ + (size_t)k * CL;
    for (int t = 0; t < CL; ++t) {
        size_t m = rowbase + t;
        float dt = delta[m * D_INNER + d];
        float u  = xc[m * D_INNER + d];
        float Bt = dbl[m * 96 + DT_RANK + n];
        float dA = expf(dt * Acoef);
        P *= dA;
        h = dA * h + (dt * u) * Bt;
    }
    size_t o = ((size_t)k * NCH + c) * D_STATE + n;
    Pout[o] = P;
    Sout[o] = h;
}

// Phase 2: serial combine over the NC chunk summaries -> incoming state per chunk
__global__ __launch_bounds__(256) void scan_phase2(const float* __restrict__ P,
                                                   const float* __restrict__ S,
                                                   float* __restrict__ hin) {
    int idx = blockIdx.x * 256 + threadIdx.x;  // NCH*16 = 65536
    float h = 0.f;
#pragma unroll
    for (int k = 0; k < NC; ++k) {
        size_t o = (size_t)k * (NCH * D_STATE) + idx;
        hin[o] = h;
        h = P[o] * h + S[o];
    }
}

// Phase 3: re-run each chunk from its incoming state, emit gated output y
__global__ __launch_bounds__(256) void scan_phase3(const float* __restrict__ delta,
                                                   const float* __restrict__ xc,
                                                   const float* __restrict__ dbl,
                                                   const float* __restrict__ z,
                                                   const float* __restrict__ A_log,
                                                   const float* __restrict__ Dp,
                                                   const float* __restrict__ hin,
                                                   float* __restrict__ y) {
    int g = blockIdx.x * 256 + threadIdx.x;
    int n  = g & 15;
    int gc = g >> 4;
    int c  = gc & (NCH - 1);
    int k  = gc >> 12;
    int d  = c & (D_INNER - 1);
    int b  = c >> 11;
    float Acoef = -expf(A_log[d * D_STATE + n]);
    float Dv = Dp[d];
    float h = hin[((size_t)k * NCH + c) * D_STATE + n];
    size_t rowbase = (size_t)b * SEQ + (size_t)k * CL;
    for (int t = 0; t < CL; ++t) {
        size_t m = rowbase + t;
        float dt = delta[m * D_INNER + d];
        float u  = xc[m * D_INNER + d];
        float Bt = dbl[m * 96 + DT_RANK + n];
        float Ct = dbl[m * 96 + DT_RANK + D_STATE + n];
        float dA = expf(dt * Acoef);
        h = dA * h + (dt * u) * Bt;
        float p = h * Ct;
        p += __shfl_xor(p, 1, 16);
        p += __shfl_xor(p, 2, 16);
        p += __shfl_xor(p, 4, 16);
        p += __shfl_xor(p, 8, 16);
        if (n == 0) {
            float zv = z[m * D_INNER + d];
            float sz = zv / (1.f + expf(-zv));
            y[m * D_INNER + d] = (p + u * Dv) * sz;
        }
    }
}

extern "C" void kernel_launch(void* const* d_in, const int* in_sizes, int n_in,
                              void* d_out, int out_size, void* d_ws, size_t ws_size,
                              hipStream_t stream) {
    const float* x       = (const float*)d_in[0];
    const float* ln_w    = (const float*)d_in[1];
    const float* ln_b    = (const float*)d_in[2];
    const float* in_proj = (const float*)d_in[3];
    const float* conv_w  = (const float*)d_in[4];
    const float* conv_b  = (const float*)d_in[5];
    const float* x_proj  = (const float*)d_in[6];
    const float* dt_w    = (const float*)d_in[7];
    const float* dt_b    = (const float*)d_in[8];
    const float* A_log   = (const float*)d_in[9];
    const float* Dp      = (const float*)d_in[10];
    const float* out_w   = (const float*)d_in[11];
    float* out = (float*)d_out;

    char* ws = (char*)d_ws;
    const size_t MB = 1024ull * 1024ull;
    float* xn    = (float*)(ws);             // 16 MB  [4096,1024]  (dead after GEMM A)
    float* x_in  = (float*)(ws + 16 * MB);   // 32 MB  [4096,2048]
    float* zbuf  = (float*)(ws + 48 * MB);   // 32 MB  [4096,2048]
    float* xc    = (float*)(ws + 80 * MB);   // 32 MB  [4096,2048]
    float* dbl   = (float*)(ws + 112 * MB);  // 1.5 MB [4096,96]
    float* delta = (float*)(ws + 114 * MB);  // 32 MB  [4096,2048]
    float* y     = x_in;                     // reuse: x_in dead after conv
    // scan summaries overlay the dead xn region (phases run after GEMM A)
    float* Pbuf  = (float*)(ws);             // 2 MB [NC,4096,16]
    float* Sbuf  = (float*)(ws + 4 * MB);    // 2 MB
    float* hin   = (float*)(ws + 8 * MB);    // 2 MB

    // 1. LayerNorm
    ln_kernel<<<NROW, 256, 0, stream>>>(x, ln_w, ln_b, xn);

    // 2. xz = xn @ in_proj^T  -> x_in | z
    gemm_tn<0><<<dim3(4096 / BN, NROW / BM), 256, 0, stream>>>(
        xn, D_MODEL, in_proj, D_MODEL, x_in, D_INNER, NROW, 2 * D_INNER, D_MODEL,
        nullptr, zbuf, D_INNER);

    // 3. causal depthwise conv + SiLU -> xc
    conv_silu<<<(NROW * (D_INNER / 4)) / 256, 256, 0, stream>>>(x_in, conv_w, conv_b, xc);

    // 4. dbl = xc @ x_proj^T   [4096, 96]
    gemm_tn<3><<<dim3((96 + BN - 1) / BN, NROW / BM), 256, 0, stream>>>(
        xc, D_INNER, x_proj, D_INNER, dbl, 96, NROW, 96, D_INNER,
        nullptr, nullptr, 0);

    // 5. delta = softplus(dt @ dt_proj^T + dt_b)   [4096, 2048]
    gemm_tn<1><<<dim3(D_INNER / BN, NROW / BM), 256, 0, stream>>>(
        dbl, 96, dt_w, DT_RANK, delta, D_INNER, NROW, D_INNER, DT_RANK,
        dt_b, nullptr, 0);

    // 6. chunked selective scan (+ skip & gate fused in phase 3)
    scan_phase1<<<(NCH * NC * D_STATE) / 256, 256, 0, stream>>>(
        delta, xc, dbl, A_log, Pbuf, Sbuf);
    scan_phase2<<<(NCH * D_STATE) / 256, 256, 0, stream>>>(Pbuf, Sbuf, hin);
    scan_phase3<<<(NCH * NC * D_STATE) / 256, 256, 0, stream>>>(
        delta, xc, dbl, zbuf, A_log, Dp, hin, y);

    // 7. out = y @ out_proj^T + x
    gemm_tn<2><<<dim3(D_MODEL / BN, NROW / BM), 256, 0, stream>>>(
        y, D_INNER, out_w, D_INNER, out, D_MODEL, NROW, D_MODEL, D_INNER,
        x, nullptr, 0);
}

// Round 3
// 683.468 us; speedup vs baseline: 3.9656x; 1.9293x over previous
//
#include <hip/hip_runtime.h>
#include <hip/hip_bf16.h>
#include <math.h>

#define D_MODEL 1024
#define D_INNER 2048
#define DT_RANK 64
#define D_STATE 16
#define BSZ 2
#define SEQ 2048
#define NROW (BSZ * SEQ)    // 4096
#define NC 8                // scan time-chunks
#define CL (SEQ / NC)       // 256 steps per chunk
#define NCH (BSZ * D_INNER) // 4096 scan channels

typedef short bf16x8 __attribute__((ext_vector_type(8)));
typedef float f32x4 __attribute__((ext_vector_type(4)));

__device__ inline ushort f2bf(float f) {
    uint32_t u = __float_as_uint(f);
    return (ushort)((u + 0x7FFFu + ((u >> 16) & 1u)) >> 16);
}

__device__ inline void gld_lds16(const void* g, void* l) {
    __builtin_amdgcn_global_load_lds(
        (__attribute__((address_space(1))) void*)g,
        (__attribute__((address_space(3))) void*)l, 16, 0, 0);
}

// ---------------- f32 -> bf16 convert (float4 -> ushort4) ----------------
__global__ __launch_bounds__(256) void cvt_bf16(const float* __restrict__ in,
                                                ushort* __restrict__ out) {
    int i = blockIdx.x * 256 + threadIdx.x;
    float4 v = ((const float4*)in)[i];
    ushort4 o;
    o.x = f2bf(v.x); o.y = f2bf(v.y); o.z = f2bf(v.z); o.w = f2bf(v.w);
    ((ushort4*)out)[i] = o;
}

// ---------------- LayerNorm -> bf16 output ----------------
__global__ __launch_bounds__(256) void ln_kernel(const float* __restrict__ x,
                                                 const float* __restrict__ w,
                                                 const float* __restrict__ b,
                                                 ushort* __restrict__ xn) {
    int row = blockIdx.x;
    int tid = threadIdx.x;
    const float4* xr = (const float4*)(x + (size_t)row * D_MODEL);
    float4 v = xr[tid];
    float s  = v.x + v.y + v.z + v.w;
    float ss = v.x * v.x + v.y * v.y + v.z * v.z + v.w * v.w;
#pragma unroll
    for (int o = 32; o > 0; o >>= 1) {
        s  += __shfl_down(s, o);
        ss += __shfl_down(ss, o);
    }
    __shared__ float red[8];
    int wid = tid >> 6, lane = tid & 63;
    if (lane == 0) { red[wid] = s; red[4 + wid] = ss; }
    __syncthreads();
    s  = red[0] + red[1] + red[2] + red[3];
    ss = red[4] + red[5] + red[6] + red[7];
    float mu  = s * (1.0f / D_MODEL);
    float var = ss * (1.0f / D_MODEL) - mu * mu;
    float inv = rsqrtf(var + 1e-5f);
    float4 wv = ((const float4*)w)[tid];
    float4 bv = ((const float4*)b)[tid];
    ushort4 o4;
    o4.x = f2bf((v.x - mu) * inv * wv.x + bv.x);
    o4.y = f2bf((v.y - mu) * inv * wv.y + bv.y);
    o4.z = f2bf((v.z - mu) * inv * wv.z + bv.z);
    o4.w = f2bf((v.w - mu) * inv * wv.w + bv.w);
    ((ushort4*)(xn + (size_t)row * D_MODEL))[tid] = o4;
}

// ---------------- bf16 MFMA GEMM: C[M,N] = A[M,K] * B[N,K]^T  (f32 out) -----------
// 128x128 tile, BK=32, 256 thr (4 waves, 2x2), 4x4 16x16x32 frags per wave,
// global_load_lds staging, double-buffered LDS, 1 barrier per K-step.
// MODE 0: split-store col<splitN -> C else C1 (col-splitN), both ld=ldc
// MODE 2: C = acc + extra[row*ldc+col]   (residual)
template <int MODE>
__global__ __launch_bounds__(256) void gemm_mfma(
    const ushort* __restrict__ A, int lda,
    const ushort* __restrict__ B, int ldb,
    float* __restrict__ C, float* __restrict__ C1, int ldc, int splitN,
    const float* __restrict__ extra, int K) {
    __shared__ ushort lds[2][2][128 * 32];
    int tid = threadIdx.x;
    int w = tid >> 6, lane = tid & 63;
    int bm = blockIdx.y * 128, bn = blockIdx.x * 128;
    int wr = w >> 1, wc = w & 1;

    // staging: thread t covers 16B at row=t>>2, seg=(t&3)*8 elems of a 64-row slab
    int srow = tid >> 2, sseg = (tid & 3) << 3;
    const ushort* Abase = A + (size_t)(bm + srow) * lda + sseg;
    const ushort* Bbase = B + (size_t)(bn + srow) * ldb + sseg;
    int l0 = w * 512;  // wave-uniform LDS elem offset (1024B per wave per issue)

    int frow = lane & 15, fk = (lane >> 4) << 3;
    f32x4 acc[4][4] = {};

#define STAGE(buf, k0)                                                        \
    do {                                                                      \
        gld_lds16(Abase + (k0),                     &lds[buf][0][l0]);        \
        gld_lds16(Abase + (size_t)64 * lda + (k0),  &lds[buf][0][2048 + l0]); \
        gld_lds16(Bbase + (k0),                     &lds[buf][1][l0]);        \
        gld_lds16(Bbase + (size_t)64 * ldb + (k0),  &lds[buf][1][2048 + l0]); \
    } while (0)

    int nk = K >> 5;
    int cur = 0;
    STAGE(0, 0);
    __syncthreads();
    for (int kt = 0; kt < nk; ++kt) {
        if (kt + 1 < nk) STAGE(cur ^ 1, (kt + 1) << 5);
        bf16x8 a[4], b[4];
#pragma unroll
        for (int m = 0; m < 4; ++m)
            a[m] = *(const bf16x8*)&lds[cur][0][(wr * 64 + m * 16 + frow) * 32 + fk];
#pragma unroll
        for (int n = 0; n < 4; ++n)
            b[n] = *(const bf16x8*)&lds[cur][1][(wc * 64 + n * 16 + frow) * 32 + fk];
#pragma unroll
        for (int m = 0; m < 4; ++m)
#pragma unroll
            for (int n = 0; n < 4; ++n)
                acc[m][n] = __builtin_amdgcn_mfma_f32_16x16x32_bf16(a[m], b[n], acc[m][n], 0, 0, 0);
        __syncthreads();
        cur ^= 1;
    }
#undef STAGE

    int rbase = bm + wr * 64 + ((lane >> 4) << 2);
    int cbase = bn + wc * 64 + (lane & 15);
#pragma unroll
    for (int m = 0; m < 4; ++m) {
#pragma unroll
        for (int n = 0; n < 4; ++n) {
            int gc = cbase + n * 16;
#pragma unroll
            for (int j = 0; j < 4; ++j) {
                int gr = rbase + m * 16 + j;
                float v = acc[m][n][j];
                if (MODE == 0) {
                    if (gc < splitN) C[(size_t)gr * ldc + gc] = v;
                    else             C1[(size_t)gr * ldc + (gc - splitN)] = v;
                } else {
                    C[(size_t)gr * ldc + gc] = v + extra[(size_t)gr * ldc + gc];
                }
            }
        }
    }
}

// ---------------- Generic f32 tiled GEMM (small GEMMs B, C) ----------------
#define BM 64
#define BN 64
#define BK 16
// MODE 1: C = softplus(acc + extra[col]); MODE 3: plain
template <int MODE>
__global__ __launch_bounds__(256) void gemm_tn(const float* __restrict__ A, int lda,
                                               const float* __restrict__ B, int ldb,
                                               float* __restrict__ C, int ldc,
                                               int M, int N, int K,
                                               const float* __restrict__ extra) {
    __shared__ float As[BK][BM];
    __shared__ float Bs[BK][BN];
    int bm = blockIdx.y * BM, bn = blockIdx.x * BN;
    int tid = threadIdx.x;
    int tx = tid & 15, ty = tid >> 4;
    int lrow = tid >> 2, lseg = (tid & 3) << 2;
    float acc[4][4] = {};

    for (int k0 = 0; k0 < K; k0 += BK) {
        float4 av = make_float4(0.f, 0.f, 0.f, 0.f);
        float4 bv = make_float4(0.f, 0.f, 0.f, 0.f);
        int agr = bm + lrow;
        if (agr < M) av = *(const float4*)(A + (size_t)agr * lda + k0 + lseg);
        int bgr = bn + lrow;
        if (bgr < N) bv = *(const float4*)(B + (size_t)bgr * ldb + k0 + lseg);
        __syncthreads();
        As[lseg + 0][lrow] = av.x; As[lseg + 1][lrow] = av.y;
        As[lseg + 2][lrow] = av.z; As[lseg + 3][lrow] = av.w;
        Bs[lseg + 0][lrow] = bv.x; Bs[lseg + 1][lrow] = bv.y;
        Bs[lseg + 2][lrow] = bv.z; Bs[lseg + 3][lrow] = bv.w;
        __syncthreads();
#pragma unroll
        for (int k = 0; k < BK; ++k) {
            float4 a4 = *(const float4*)&As[k][ty << 2];
            float4 b4 = *(const float4*)&Bs[k][tx << 2];
            float ar[4] = {a4.x, a4.y, a4.z, a4.w};
            float br[4] = {b4.x, b4.y, b4.z, b4.w};
#pragma unroll
            for (int i = 0; i < 4; ++i)
#pragma unroll
                for (int j = 0; j < 4; ++j) acc[i][j] += ar[i] * br[j];
        }
    }

#pragma unroll
    for (int i = 0; i < 4; ++i) {
        int gr = bm + (ty << 2) + i;
        if (gr >= M) continue;
#pragma unroll
        for (int j = 0; j < 4; ++j) {
            int gc = bn + (tx << 2) + j;
            if (gc >= N) continue;
            float v = acc[i][j];
            if (MODE == 1) {
                v += extra[gc];
                v = (v > 20.f) ? v : log1pf(expf(v));
                C[(size_t)gr * ldc + gc] = v;
            } else {
                C[(size_t)gr * ldc + gc] = v;
            }
        }
    }
}

// ---------------- causal depthwise conv1d (k=4, left pad 3) + SiLU ----------------
__global__ __launch_bounds__(256) void conv_silu(const float* __restrict__ xin,
                                                 const float* __restrict__ w,
                                                 const float* __restrict__ cb,
                                                 float* __restrict__ xc) {
    int idx = blockIdx.x * 256 + threadIdx.x;
    int d4 = idx & 511;
    int m  = idx >> 9;
    int l  = m & (SEQ - 1);
    int d  = d4 << 2;
    float4 w0 = ((const float4*)w)[d + 0];
    float4 w1 = ((const float4*)w)[d + 1];
    float4 w2 = ((const float4*)w)[d + 2];
    float4 w3 = ((const float4*)w)[d + 3];
    float wr0[4] = {w0.x, w0.y, w0.z, w0.w};
    float wr1[4] = {w1.x, w1.y, w1.z, w1.w};
    float wr2[4] = {w2.x, w2.y, w2.z, w2.w};
    float wr3[4] = {w3.x, w3.y, w3.z, w3.w};
    float ax = cb[d], ay = cb[d + 1], az = cb[d + 2], aw = cb[d + 3];
#pragma unroll
    for (int j = 0; j < 4; ++j) {
        if (l - 3 + j >= 0) {
            float4 xv = *(const float4*)(xin + (size_t)(m - 3 + j) * D_INNER + d);
            ax += wr0[j] * xv.x;
            ay += wr1[j] * xv.y;
            az += wr2[j] * xv.z;
            aw += wr3[j] * xv.w;
        }
    }
    float4 o;
    o.x = ax / (1.f + expf(-ax));
    o.y = ay / (1.f + expf(-ay));
    o.z = az / (1.f + expf(-az));
    o.w = aw / (1.f + expf(-aw));
    *(float4*)(xc + (size_t)m * D_INNER + d) = o;
}

// ---------------- chunked selective scan ------------------------------------------
__global__ __launch_bounds__(256) void scan_phase1(const float* __restrict__ delta,
                                                   const float* __restrict__ xc,
                                                   const float* __restrict__ dbl,
                                                   const float* __restrict__ A_log,
                                                   float* __restrict__ Pout,
                                                   float* __restrict__ Sout) {
    int g = blockIdx.x * 256 + threadIdx.x;
    int n  = g & 15;
    int gc = g >> 4;
    int c  = gc & (NCH - 1);
    int k  = gc >> 12;
    int d  = c & (D_INNER - 1);
    int b  = c >> 11;
    float Acoef = -expf(A_log[d * D_STATE + n]);
    float P = 1.f, h = 0.f;
    size_t rowbase = (size_t)b * SEQ + (size_t)k * CL;
    for (int t = 0; t < CL; ++t) {
        size_t m = rowbase + t;
        float dt = delta[m * D_INNER + d];
        float u  = xc[m * D_INNER + d];
        float Bt = dbl[m * 96 + DT_RANK + n];
        float dA = expf(dt * Acoef);
        P *= dA;
        h = dA * h + (dt * u) * Bt;
    }
    size_t o = ((size_t)k * NCH + c) * D_STATE + n;
    Pout[o] = P;
    Sout[o] = h;
}

__global__ __launch_bounds__(256) void scan_phase2(const float* __restrict__ P,
                                                   const float* __restrict__ S,
                                                   float* __restrict__ hin) {
    int idx = blockIdx.x * 256 + threadIdx.x;
    float h = 0.f;
#pragma unroll
    for (int k = 0; k < NC; ++k) {
        size_t o = (size_t)k * (NCH * D_STATE) + idx;
        hin[o] = h;
        h = P[o] * h + S[o];
    }
}

__global__ __launch_bounds__(256) void scan_phase3(const float* __restrict__ delta,
                                                   const float* __restrict__ xc,
                                                   const float* __restrict__ dbl,
                                                   const float* __restrict__ z,
                                                   const float* __restrict__ A_log,
                                                   const float* __restrict__ Dp,
                                                   const float* __restrict__ hin,
                                                   ushort* __restrict__ y) {
    int g = blockIdx.x * 256 + threadIdx.x;
    int n  = g & 15;
    int gc = g >> 4;
    int c  = gc & (NCH - 1);
    int k  = gc >> 12;
    int d  = c & (D_INNER - 1);
    int b  = c >> 11;
    float Acoef = -expf(A_log[d * D_STATE + n]);
    float Dv = Dp[d];
    float h = hin[((size_t)k * NCH + c) * D_STATE + n];
    size_t rowbase = (size_t)b * SEQ + (size_t)k * CL;
    for (int t = 0; t < CL; ++t) {
        size_t m = rowbase + t;
        float dt = delta[m * D_INNER + d];
        float u  = xc[m * D_INNER + d];
        float Bt = dbl[m * 96 + DT_RANK + n];
        float Ct = dbl[m * 96 + DT_RANK + D_STATE + n];
        float dA = expf(dt * Acoef);
        h = dA * h + (dt * u) * Bt;
        float p = h * Ct;
        p += __shfl_xor(p, 1, 16);
        p += __shfl_xor(p, 2, 16);
        p += __shfl_xor(p, 4, 16);
        p += __shfl_xor(p, 8, 16);
        if (n == 0) {
            float zv = z[m * D_INNER + d];
            float sz = zv / (1.f + expf(-zv));
            y[m * D_INNER + d] = f2bf((p + u * Dv) * sz);
        }
    }
}

extern "C" void kernel_launch(void* const* d_in, const int* in_sizes, int n_in,
                              void* d_out, int out_size, void* d_ws, size_t ws_size,
                              hipStream_t stream) {
    const float* x       = (const float*)d_in[0];
    const float* ln_w    = (const float*)d_in[1];
    const float* ln_b    = (const float*)d_in[2];
    const float* in_proj = (const float*)d_in[3];
    const float* conv_w  = (const float*)d_in[4];
    const float* conv_b  = (const float*)d_in[5];
    const float* x_proj  = (const float*)d_in[6];
    const float* dt_w    = (const float*)d_in[7];
    const float* dt_b    = (const float*)d_in[8];
    const float* A_log   = (const float*)d_in[9];
    const float* Dp      = (const float*)d_in[10];
    const float* out_w   = (const float*)d_in[11];
    float* out = (float*)d_out;

    char* ws = (char*)d_ws;
    const size_t MB = 1024ull * 1024ull;
    // lifetimes: see round-2 notes. 146 MB total (proven fits).
    ushort* xn_bf   = (ushort*)(ws);              // [0,8)    LN -> GEMM A
    ushort* w_in_bf = (ushort*)(ws + 8 * MB);     // [8,16)   cvt -> GEMM A
    float*  x_in    = (float*)(ws + 16 * MB);     // [16,48)  GEMM A -> conv
    float*  zbuf    = (float*)(ws + 48 * MB);     // [48,80)  GEMM A -> phase3
    float*  xc      = (float*)(ws + 80 * MB);     // [80,112) conv -> phase3
    float*  dbl     = (float*)(ws + 112 * MB);    // [112,114)
    float*  delta   = (float*)(ws + 114 * MB);    // [114,146) GEMM C -> phase3
    // overlays on dead x_in region (free after conv):
    ushort* y_bf    = (ushort*)(ws + 16 * MB);    // [16,32)  phase3 -> GEMM D
    ushort* w_out_bf= (ushort*)(ws + 32 * MB);    // [32,36)  cvt(after conv) -> GEMM D
    float*  Pbuf    = (float*)(ws + 36 * MB);     // [36,38)
    float*  Sbuf    = (float*)(ws + 38 * MB);     // [38,40)
    float*  hin     = (float*)(ws + 40 * MB);     // [40,42)

    // 0. convert in_proj weights to bf16 (4096x1024)
    cvt_bf16<<<(2 * D_INNER * D_MODEL / 4) / 256, 256, 0, stream>>>(in_proj, w_in_bf);

    // 1. LayerNorm -> bf16
    ln_kernel<<<NROW, 256, 0, stream>>>(x, ln_w, ln_b, xn_bf);

    // 2. xz = xn @ in_proj^T  -> x_in | z   (bf16 MFMA)
    gemm_mfma<0><<<dim3(4096 / 128, NROW / 128), 256, 0, stream>>>(
        xn_bf, D_MODEL, w_in_bf, D_MODEL, x_in, zbuf, D_INNER, D_INNER,
        nullptr, D_MODEL);

    // 3. causal depthwise conv + SiLU -> xc
    conv_silu<<<(NROW * (D_INNER / 4)) / 256, 256, 0, stream>>>(x_in, conv_w, conv_b, xc);

    // 3b. convert out_proj weights to bf16 (1024x2048) — region free after conv
    cvt_bf16<<<(D_MODEL * D_INNER / 4) / 256, 256, 0, stream>>>(out_w, w_out_bf);

    // 4. dbl = xc @ x_proj^T   [4096, 96]
    gemm_tn<3><<<dim3((96 + BN - 1) / BN, NROW / BM), 256, 0, stream>>>(
        xc, D_INNER, x_proj, D_INNER, dbl, 96, NROW, 96, D_INNER, nullptr);

    // 5. delta = softplus(dt @ dt_proj^T + dt_b)   [4096, 2048]
    gemm_tn<1><<<dim3(D_INNER / BN, NROW / BM), 256, 0, stream>>>(
        dbl, 96, dt_w, DT_RANK, delta, D_INNER, NROW, D_INNER, DT_RANK, dt_b);

    // 6. chunked selective scan (+ skip & gate fused in phase 3, emits bf16 y)
    scan_phase1<<<(NCH * NC * D_STATE) / 256, 256, 0, stream>>>(
        delta, xc, dbl, A_log, Pbuf, Sbuf);
    scan_phase2<<<(NCH * D_STATE) / 256, 256, 0, stream>>>(Pbuf, Sbuf, hin);
    scan_phase3<<<(NCH * NC * D_STATE) / 256, 256, 0, stream>>>(
        delta, xc, dbl, zbuf, A_log, Dp, hin, y_bf);

    // 7. out = y @ out_proj^T + x   (bf16 MFMA, residual epilogue)
    gemm_mfma<2><<<dim3(D_MODEL / 128, NROW / 128), 256, 0, stream>>>(
        y_bf, D_INNER, w_out_bf, D_INNER, out, nullptr, D_MODEL, 0,
        x, D_INNER);
}

// Round 5
// 524.092 us; speedup vs baseline: 5.1715x; 1.3041x over previous
//
#include <hip/hip_runtime.h>
#include <hip/hip_bf16.h>
#include <math.h>

#define D_MODEL 1024
#define D_INNER 2048
#define DT_RANK 64
#define D_STATE 16
#define BSZ 2
#define SEQ 2048
#define NROW (BSZ * SEQ)    // 4096
#define NC 64               // scan time-chunks
#define CL (SEQ / NC)       // 32 steps per chunk
#define NCH (BSZ * D_INNER) // 4096 scan channels

typedef short bf16x8 __attribute__((ext_vector_type(8)));
typedef float f32x4 __attribute__((ext_vector_type(4)));

__device__ inline ushort f2bf(float f) {
    uint32_t u = __float_as_uint(f);
    return (ushort)((u + 0x7FFFu + ((u >> 16) & 1u)) >> 16);
}
__device__ inline float bf2f(ushort u) {
    return __uint_as_float(((uint32_t)u) << 16);
}

__device__ inline void gld_lds16(const void* g, void* l) {
    __builtin_amdgcn_global_load_lds(
        (__attribute__((address_space(1))) void*)g,
        (__attribute__((address_space(3))) void*)l, 16, 0, 0);
}

// ---------------- f32 -> bf16 convert (float4 -> ushort4) ----------------
__global__ __launch_bounds__(256) void cvt_bf16(const float* __restrict__ in,
                                                ushort* __restrict__ out) {
    int i = blockIdx.x * 256 + threadIdx.x;
    float4 v = ((const float4*)in)[i];
    ushort4 o;
    o.x = f2bf(v.x); o.y = f2bf(v.y); o.z = f2bf(v.z); o.w = f2bf(v.w);
    ((ushort4*)out)[i] = o;
}

// ---------------- LayerNorm -> bf16 output ----------------
__global__ __launch_bounds__(256) void ln_kernel(const float* __restrict__ x,
                                                 const float* __restrict__ w,
                                                 const float* __restrict__ b,
                                                 ushort* __restrict__ xn) {
    int row = blockIdx.x;
    int tid = threadIdx.x;
    const float4* xr = (const float4*)(x + (size_t)row * D_MODEL);
    float4 v = xr[tid];
    float s  = v.x + v.y + v.z + v.w;
    float ss = v.x * v.x + v.y * v.y + v.z * v.z + v.w * v.w;
#pragma unroll
    for (int o = 32; o > 0; o >>= 1) {
        s  += __shfl_down(s, o);
        ss += __shfl_down(ss, o);
    }
    __shared__ float red[8];
    int wid = tid >> 6, lane = tid & 63;
    if (lane == 0) { red[wid] = s; red[4 + wid] = ss; }
    __syncthreads();
    s  = red[0] + red[1] + red[2] + red[3];
    ss = red[4] + red[5] + red[6] + red[7];
    float mu  = s * (1.0f / D_MODEL);
    float var = ss * (1.0f / D_MODEL) - mu * mu;
    float inv = rsqrtf(var + 1e-5f);
    float4 wv = ((const float4*)w)[tid];
    float4 bv = ((const float4*)b)[tid];
    ushort4 o4;
    o4.x = f2bf((v.x - mu) * inv * wv.x + bv.x);
    o4.y = f2bf((v.y - mu) * inv * wv.y + bv.y);
    o4.z = f2bf((v.z - mu) * inv * wv.z + bv.z);
    o4.w = f2bf((v.w - mu) * inv * wv.w + bv.w);
    ((ushort4*)(xn + (size_t)row * D_MODEL))[tid] = o4;
}

// ---------------- bf16 MFMA GEMM: C[M,N] = A[M,K] * B[N,K]^T  (f32 out) -----------
// MODE 0: col<splitN -> C (f32); col>=splitN -> Zb (bf16, col-splitN), both ld=ldc
// MODE 2: C = acc + extra[row*ldc+col]   (residual)
template <int MODE>
__global__ __launch_bounds__(256) void gemm_mfma(
    const ushort* __restrict__ A, int lda,
    const ushort* __restrict__ B, int ldb,
    float* __restrict__ C, ushort* __restrict__ Zb, int ldc, int splitN,
    const float* __restrict__ extra, int K) {
    __shared__ ushort lds[2][2][128 * 32];
    int tid = threadIdx.x;
    int w = tid >> 6, lane = tid & 63;
    int bm = blockIdx.y * 128, bn = blockIdx.x * 128;
    int wr = w >> 1, wc = w & 1;

    int srow = tid >> 2, sseg = (tid & 3) << 3;
    const ushort* Abase = A + (size_t)(bm + srow) * lda + sseg;
    const ushort* Bbase = B + (size_t)(bn + srow) * ldb + sseg;
    int l0 = w * 512;

    int frow = lane & 15, fk = (lane >> 4) << 3;
    f32x4 acc[4][4] = {};

#define STAGE(buf, k0)                                                        \
    do {                                                                      \
        gld_lds16(Abase + (k0),                     &lds[buf][0][l0]);        \
        gld_lds16(Abase + (size_t)64 * lda + (k0),  &lds[buf][0][2048 + l0]); \
        gld_lds16(Bbase + (k0),                     &lds[buf][1][l0]);        \
        gld_lds16(Bbase + (size_t)64 * ldb + (k0),  &lds[buf][1][2048 + l0]); \
    } while (0)

    int nk = K >> 5;
    int cur = 0;
    STAGE(0, 0);
    __syncthreads();
    for (int kt = 0; kt < nk; ++kt) {
        if (kt + 1 < nk) STAGE(cur ^ 1, (kt + 1) << 5);
        bf16x8 a[4], b[4];
#pragma unroll
        for (int m = 0; m < 4; ++m)
            a[m] = *(const bf16x8*)&lds[cur][0][(wr * 64 + m * 16 + frow) * 32 + fk];
#pragma unroll
        for (int n = 0; n < 4; ++n)
            b[n] = *(const bf16x8*)&lds[cur][1][(wc * 64 + n * 16 + frow) * 32 + fk];
#pragma unroll
        for (int m = 0; m < 4; ++m)
#pragma unroll
            for (int n = 0; n < 4; ++n)
                acc[m][n] = __builtin_amdgcn_mfma_f32_16x16x32_bf16(a[m], b[n], acc[m][n], 0, 0, 0);
        __syncthreads();
        cur ^= 1;
    }
#undef STAGE

    int rbase = bm + wr * 64 + ((lane >> 4) << 2);
    int cbase = bn + wc * 64 + (lane & 15);
#pragma unroll
    for (int m = 0; m < 4; ++m) {
#pragma unroll
        for (int n = 0; n < 4; ++n) {
            int gc = cbase + n * 16;
#pragma unroll
            for (int j = 0; j < 4; ++j) {
                int gr = rbase + m * 16 + j;
                float v = acc[m][n][j];
                if (MODE == 0) {
                    if (gc < splitN) C[(size_t)gr * ldc + gc] = v;
                    else             Zb[(size_t)gr * ldc + (gc - splitN)] = f2bf(v);
                } else {
                    C[(size_t)gr * ldc + gc] = v + extra[(size_t)gr * ldc + gc];
                }
            }
        }
    }
}

// ---------------- Generic f32 tiled GEMM (small GEMMs B, C) ----------------
#define BM 64
#define BN 64
#define BK 16
// MODE 1: C = softplus(acc + extra[col]); MODE 3: plain
template <int MODE>
__global__ __launch_bounds__(256) void gemm_tn(const float* __restrict__ A, int lda,
                                               const float* __restrict__ B, int ldb,
                                               float* __restrict__ C, int ldc,
                                               int M, int N, int K,
                                               const float* __restrict__ extra) {
    __shared__ float As[BK][BM];
    __shared__ float Bs[BK][BN];
    int bm = blockIdx.y * BM, bn = blockIdx.x * BN;
    int tid = threadIdx.x;
    int tx = tid & 15, ty = tid >> 4;
    int lrow = tid >> 2, lseg = (tid & 3) << 2;
    float acc[4][4] = {};

    for (int k0 = 0; k0 < K; k0 += BK) {
        float4 av = make_float4(0.f, 0.f, 0.f, 0.f);
        float4 bv = make_float4(0.f, 0.f, 0.f, 0.f);
        int agr = bm + lrow;
        if (agr < M) av = *(const float4*)(A + (size_t)agr * lda + k0 + lseg);
        int bgr = bn + lrow;
        if (bgr < N) bv = *(const float4*)(B + (size_t)bgr * ldb + k0 + lseg);
        __syncthreads();
        As[lseg + 0][lrow] = av.x; As[lseg + 1][lrow] = av.y;
        As[lseg + 2][lrow] = av.z; As[lseg + 3][lrow] = av.w;
        Bs[lseg + 0][lrow] = bv.x; Bs[lseg + 1][lrow] = bv.y;
        Bs[lseg + 2][lrow] = bv.z; Bs[lseg + 3][lrow] = bv.w;
        __syncthreads();
#pragma unroll
        for (int k = 0; k < BK; ++k) {
            float4 a4 = *(const float4*)&As[k][ty << 2];
            float4 b4 = *(const float4*)&Bs[k][tx << 2];
            float ar[4] = {a4.x, a4.y, a4.z, a4.w};
            float br[4] = {b4.x, b4.y, b4.z, b4.w};
#pragma unroll
            for (int i = 0; i < 4; ++i)
#pragma unroll
                for (int j = 0; j < 4; ++j) acc[i][j] += ar[i] * br[j];
        }
    }

#pragma unroll
    for (int i = 0; i < 4; ++i) {
        int gr = bm + (ty << 2) + i;
        if (gr >= M) continue;
#pragma unroll
        for (int j = 0; j < 4; ++j) {
            int gc = bn + (tx << 2) + j;
            if (gc >= N) continue;
            float v = acc[i][j];
            if (MODE == 1) {
                v += extra[gc];
                v = (v > 20.f) ? v : log1pf(expf(v));
                C[(size_t)gr * ldc + gc] = v;
            } else {
                C[(size_t)gr * ldc + gc] = v;
            }
        }
    }
}

// ---------------- causal depthwise conv1d (k=4, left pad 3) + SiLU ----------------
__global__ __launch_bounds__(256) void conv_silu(const float* __restrict__ xin,
                                                 const float* __restrict__ w,
                                                 const float* __restrict__ cb,
                                                 float* __restrict__ xc) {
    int idx = blockIdx.x * 256 + threadIdx.x;
    int d4 = idx & 511;
    int m  = idx >> 9;
    int l  = m & (SEQ - 1);
    int d  = d4 << 2;
    float4 w0 = ((const float4*)w)[d + 0];
    float4 w1 = ((const float4*)w)[d + 1];
    float4 w2 = ((const float4*)w)[d + 2];
    float4 w3 = ((const float4*)w)[d + 3];
    float wr0[4] = {w0.x, w0.y, w0.z, w0.w};
    float wr1[4] = {w1.x, w1.y, w1.z, w1.w};
    float wr2[4] = {w2.x, w2.y, w2.z, w2.w};
    float wr3[4] = {w3.x, w3.y, w3.z, w3.w};
    float ax = cb[d], ay = cb[d + 1], az = cb[d + 2], aw = cb[d + 3];
#pragma unroll
    for (int j = 0; j < 4; ++j) {
        if (l - 3 + j >= 0) {
            float4 xv = *(const float4*)(xin + (size_t)(m - 3 + j) * D_INNER + d);
            ax += wr0[j] * xv.x;
            ay += wr1[j] * xv.y;
            az += wr2[j] * xv.z;
            aw += wr3[j] * xv.w;
        }
    }
    float4 o;
    o.x = ax / (1.f + __expf(-ax));
    o.y = ay / (1.f + __expf(-ay));
    o.z = az / (1.f + __expf(-az));
    o.w = aw / (1.f + __expf(-aw));
    *(float4*)(xc + (size_t)m * D_INNER + d) = o;
}

// ---------------- chunked selective scan, 16 states per thread --------------------
// thread g -> channel c = g & 4095, chunk k = g >> 12
#define EXP4(e, cj) \
    e.x = __expf(dt * cj.x); e.y = __expf(dt * cj.y); \
    e.z = __expf(dt * cj.z); e.w = __expf(dt * cj.w);
#define HUPD(hj, cj, Bv) { float4 e; EXP4(e, cj) \
    hj.x = e.x * hj.x + du * Bv.x; hj.y = e.y * hj.y + du * Bv.y; \
    hj.z = e.z * hj.z + du * Bv.z; hj.w = e.w * hj.w + du * Bv.w; }

__global__ __launch_bounds__(256) void scan_phase1(const float* __restrict__ delta,
                                                   const float* __restrict__ xc,
                                                   const float* __restrict__ dbl,
                                                   const float* __restrict__ A_log,
                                                   float* __restrict__ S,
                                                   float* __restrict__ sumdt) {
    int g = blockIdx.x * 256 + threadIdx.x;   // 262144
    int c = g & (NCH - 1);
    int k = g >> 12;
    int d = c & (D_INNER - 1);
    int b = c >> 11;
    const float4* al = (const float4*)(A_log + d * D_STATE);
    float4 c0 = al[0], c1 = al[1], c2 = al[2], c3 = al[3];
    c0.x = -__expf(c0.x); c0.y = -__expf(c0.y); c0.z = -__expf(c0.z); c0.w = -__expf(c0.w);
    c1.x = -__expf(c1.x); c1.y = -__expf(c1.y); c1.z = -__expf(c1.z); c1.w = -__expf(c1.w);
    c2.x = -__expf(c2.x); c2.y = -__expf(c2.y); c2.z = -__expf(c2.z); c2.w = -__expf(c2.w);
    c3.x = -__expf(c3.x); c3.y = -__expf(c3.y); c3.z = -__expf(c3.z); c3.w = -__expf(c3.w);

    size_t r0 = (size_t)b * SEQ + (size_t)k * CL;
    const float* pd = delta + r0 * D_INNER + d;
    const float* pu = xc    + r0 * D_INNER + d;
    const float4* pB = (const float4*)(dbl + r0 * 96 + DT_RANK);
    float4 h0 = {}, h1 = {}, h2 = {}, h3 = {};
    float sdt = 0.f;
    for (int t = 0; t < CL; ++t) {
        float dt = *pd, u = *pu;
        float4 B0 = pB[0], B1 = pB[1], B2 = pB[2], B3 = pB[3];
        float du = dt * u;
        sdt += dt;
        HUPD(h0, c0, B0) HUPD(h1, c1, B1) HUPD(h2, c2, B2) HUPD(h3, c3, B3)
        pd += D_INNER; pu += D_INNER; pB += 24;
    }
    float4* So = (float4*)(S + ((size_t)g << 4));
    So[0] = h0; So[1] = h1; So[2] = h2; So[3] = h3;
    sumdt[g] = sdt;
}

// phase2: combine chunk summaries serially; hin written in-place over S
__global__ __launch_bounds__(256) void scan_phase2(float* __restrict__ S,
                                                   const float* __restrict__ sumdt,
                                                   const float* __restrict__ A_log) {
    int g = blockIdx.x * 256 + threadIdx.x;  // 65536
    int n = g & 15;
    int c = g >> 4;
    int d = c & (D_INNER - 1);
    float cn = -__expf(A_log[d * D_STATE + n]);
    float h = 0.f;
#pragma unroll 8
    for (int k = 0; k < NC; ++k) {
        int kc = (k << 12) | c;
        float P = __expf(sumdt[kc] * cn);
        size_t o = ((size_t)kc << 4) + n;
        float s = S[o];
        S[o] = h;              // hin for chunk k
        h = P * h + s;
    }
}

__global__ __launch_bounds__(256) void scan_phase3(const float* __restrict__ delta,
                                                   const float* __restrict__ xc,
                                                   const float* __restrict__ dbl,
                                                   const ushort* __restrict__ zb,
                                                   const float* __restrict__ A_log,
                                                   const float* __restrict__ Dp,
                                                   const float* __restrict__ hin,
                                                   ushort* __restrict__ y) {
    int g = blockIdx.x * 256 + threadIdx.x;
    int c = g & (NCH - 1);
    int k = g >> 12;
    int d = c & (D_INNER - 1);
    int b = c >> 11;
    const float4* al = (const float4*)(A_log + d * D_STATE);
    float4 c0 = al[0], c1 = al[1], c2 = al[2], c3 = al[3];
    c0.x = -__expf(c0.x); c0.y = -__expf(c0.y); c0.z = -__expf(c0.z); c0.w = -__expf(c0.w);
    c1.x = -__expf(c1.x); c1.y = -__expf(c1.y); c1.z = -__expf(c1.z); c1.w = -__expf(c1.w);
    c2.x = -__expf(c2.x); c2.y = -__expf(c2.y); c2.z = -__expf(c2.z); c2.w = -__expf(c2.w);
    c3.x = -__expf(c3.x); c3.y = -__expf(c3.y); c3.z = -__expf(c3.z); c3.w = -__expf(c3.w);
    float Dv = Dp[d];
    const float4* hi = (const float4*)(hin + ((size_t)g << 4));
    float4 h0 = hi[0], h1 = hi[1], h2 = hi[2], h3 = hi[3];

    size_t r0 = (size_t)b * SEQ + (size_t)k * CL;
    const float* pd = delta + r0 * D_INNER + d;
    const float* pu = xc    + r0 * D_INNER + d;
    const ushort* pz = zb   + r0 * D_INNER + d;
    ushort* py = y          + r0 * D_INNER + d;
    const float4* pB = (const float4*)(dbl + r0 * 96 + DT_RANK);
    for (int t = 0; t < CL; ++t) {
        float dt = *pd, u = *pu;
        float4 B0 = pB[0], B1 = pB[1], B2 = pB[2], B3 = pB[3];
        float4 C0 = pB[4], C1 = pB[5], C2 = pB[6], C3 = pB[7];
        float du = dt * u;
        HUPD(h0, c0, B0) HUPD(h1, c1, B1) HUPD(h2, c2, B2) HUPD(h3, c3, B3)
        float acc = h0.x * C0.x + h0.y * C0.y + h0.z * C0.z + h0.w * C0.w
                  + h1.x * C1.x + h1.y * C1.y + h1.z * C1.z + h1.w * C1.w
                  + h2.x * C2.x + h2.y * C2.y + h2.z * C2.z + h2.w * C2.w
                  + h3.x * C3.x + h3.y * C3.y + h3.z * C3.z + h3.w * C3.w;
        float zv = bf2f(*pz);
        float sz = zv / (1.f + __expf(-zv));
        *py = f2bf((acc + u * Dv) * sz);
        pd += D_INNER; pu += D_INNER; pz += D_INNER; py += D_INNER; pB += 24;
    }
}

extern "C" void kernel_launch(void* const* d_in, const int* in_sizes, int n_in,
                              void* d_out, int out_size, void* d_ws, size_t ws_size,
                              hipStream_t stream) {
    const float* x       = (const float*)d_in[0];
    const float* ln_w    = (const float*)d_in[1];
    const float* ln_b    = (const float*)d_in[2];
    const float* in_proj = (const float*)d_in[3];
    const float* conv_w  = (const float*)d_in[4];
    const float* conv_b  = (const float*)d_in[5];
    const float* x_proj  = (const float*)d_in[6];
    const float* dt_w    = (const float*)d_in[7];
    const float* dt_b    = (const float*)d_in[8];
    const float* A_log   = (const float*)d_in[9];
    const float* Dp      = (const float*)d_in[10];
    const float* out_w   = (const float*)d_in[11];
    float* out = (float*)d_out;

    char* ws = (char*)d_ws;
    const size_t MB = 1024ull * 1024ull;
    // Layout (fixed round-4 overflow: zbuf_bf needs 16 MB, not 8):
    // [0,8)    xn_bf (LN -> GEMM A)
    // [8,16)   w_in_bf (cvt -> GEMM A)
    // [0,16)   Shin overlay (phase1 -> phase2 -> phase3; after GEMM A)
    // [16,48)  x_in f32 (GEMM A -> conv); after conv overlaid by:
    //            y_bf [16,32), w_out_bf [32,36), sumdt [36,37)
    // [48,64)  zbuf_bf 16 MB (GEMM A -> phase3)
    // [64,96)  xc f32 (conv -> phase1/3, GEMM B)
    // [96,98)  dbl (GEMM B -> GEMM C, phase1/3)
    // [98,130) delta (GEMM C -> phase1/3)
    ushort* xn_bf    = (ushort*)(ws);
    ushort* w_in_bf  = (ushort*)(ws + 8 * MB);
    float*  Shin     = (float*)(ws);              // 16 MB: NC*NCH*16 f32
    float*  x_in     = (float*)(ws + 16 * MB);
    ushort* y_bf     = (ushort*)(ws + 16 * MB);
    ushort* w_out_bf = (ushort*)(ws + 32 * MB);
    float*  sumdt    = (float*)(ws + 36 * MB);    // 1 MB: NC*NCH f32
    ushort* zbuf_bf  = (ushort*)(ws + 48 * MB);   // 16 MB
    float*  xc       = (float*)(ws + 64 * MB);
    float*  dbl      = (float*)(ws + 96 * MB);
    float*  delta    = (float*)(ws + 98 * MB);

    // 0. convert in_proj weights to bf16 (4096x1024)
    cvt_bf16<<<(2 * D_INNER * D_MODEL / 4) / 256, 256, 0, stream>>>(in_proj, w_in_bf);

    // 1. LayerNorm -> bf16
    ln_kernel<<<NROW, 256, 0, stream>>>(x, ln_w, ln_b, xn_bf);

    // 2. xz = xn @ in_proj^T  -> x_in (f32) | z (bf16)
    gemm_mfma<0><<<dim3(4096 / 128, NROW / 128), 256, 0, stream>>>(
        xn_bf, D_MODEL, w_in_bf, D_MODEL, x_in, zbuf_bf, D_INNER, D_INNER,
        nullptr, D_MODEL);

    // 3. causal depthwise conv + SiLU -> xc
    conv_silu<<<(NROW * (D_INNER / 4)) / 256, 256, 0, stream>>>(x_in, conv_w, conv_b, xc);

    // 3b. convert out_proj weights to bf16 (region free after conv)
    cvt_bf16<<<(D_MODEL * D_INNER / 4) / 256, 256, 0, stream>>>(out_w, w_out_bf);

    // 4. dbl = xc @ x_proj^T   [4096, 96]
    gemm_tn<3><<<dim3((96 + BN - 1) / BN, NROW / BM), 256, 0, stream>>>(
        xc, D_INNER, x_proj, D_INNER, dbl, 96, NROW, 96, D_INNER, nullptr);

    // 5. delta = softplus(dt @ dt_proj^T + dt_b)   [4096, 2048]
    gemm_tn<1><<<dim3(D_INNER / BN, NROW / BM), 256, 0, stream>>>(
        dbl, 96, dt_w, DT_RANK, delta, D_INNER, NROW, D_INNER, DT_RANK, dt_b);

    // 6. chunked selective scan (16 states/thread; skip & gate fused in phase 3)
    scan_phase1<<<(NCH * NC) / 256, 256, 0, stream>>>(
        delta, xc, dbl, A_log, Shin, sumdt);
    scan_phase2<<<(NCH * D_STATE) / 256, 256, 0, stream>>>(Shin, sumdt, A_log);
    scan_phase3<<<(NCH * NC) / 256, 256, 0, stream>>>(
        delta, xc, dbl, zbuf_bf, A_log, Dp, Shin, y_bf);

    // 7. out = y @ out_proj^T + x   (bf16 MFMA, residual epilogue)
    gemm_mfma<2><<<dim3(D_MODEL / 128, NROW / 128), 256, 0, stream>>>(
        y_bf, D_INNER, w_out_bf, D_INNER, out, nullptr, D_MODEL, 0,
        x, D_INNER);
}

// Round 6
// 442.945 us; speedup vs baseline: 6.1189x; 1.1832x over previous
//
#include <hip/hip_runtime.h>
#include <hip/hip_bf16.h>
#include <math.h>

#define D_MODEL 1024
#define D_INNER 2048
#define DT_RANK 64
#define D_STATE 16
#define BSZ 2
#define SEQ 2048
#define NROW (BSZ * SEQ)    // 4096
#define NC 64               // scan time-chunks
#define CL (SEQ / NC)       // 32 steps per chunk
#define NCH (BSZ * D_INNER) // 4096 scan channels
#define KSPLIT 16           // GEMM B K-split
#define KCH (D_INNER / KSPLIT) // 128

typedef short bf16x8 __attribute__((ext_vector_type(8)));
typedef float f32x4 __attribute__((ext_vector_type(4)));

__device__ inline ushort f2bf(float f) {
    uint32_t u = __float_as_uint(f);
    return (ushort)((u + 0x7FFFu + ((u >> 16) & 1u)) >> 16);
}
__device__ inline float bf2f(ushort u) {
    return __uint_as_float(((uint32_t)u) << 16);
}

__device__ inline void gld_lds16(const void* g, void* l) {
    __builtin_amdgcn_global_load_lds(
        (__attribute__((address_space(1))) void*)g,
        (__attribute__((address_space(3))) void*)l, 16, 0, 0);
}

// ---------------- f32 -> bf16 convert (float4 -> ushort4) ----------------
__global__ __launch_bounds__(256) void cvt_bf16(const float* __restrict__ in,
                                                ushort* __restrict__ out) {
    int i = blockIdx.x * 256 + threadIdx.x;
    float4 v = ((const float4*)in)[i];
    ushort4 o;
    o.x = f2bf(v.x); o.y = f2bf(v.y); o.z = f2bf(v.z); o.w = f2bf(v.w);
    ((ushort4*)out)[i] = o;
}

// ---------------- LayerNorm -> bf16 output ----------------
__global__ __launch_bounds__(256) void ln_kernel(const float* __restrict__ x,
                                                 const float* __restrict__ w,
                                                 const float* __restrict__ b,
                                                 ushort* __restrict__ xn) {
    int row = blockIdx.x;
    int tid = threadIdx.x;
    const float4* xr = (const float4*)(x + (size_t)row * D_MODEL);
    float4 v = xr[tid];
    float s  = v.x + v.y + v.z + v.w;
    float ss = v.x * v.x + v.y * v.y + v.z * v.z + v.w * v.w;
#pragma unroll
    for (int o = 32; o > 0; o >>= 1) {
        s  += __shfl_down(s, o);
        ss += __shfl_down(ss, o);
    }
    __shared__ float red[8];
    int wid = tid >> 6, lane = tid & 63;
    if (lane == 0) { red[wid] = s; red[4 + wid] = ss; }
    __syncthreads();
    s  = red[0] + red[1] + red[2] + red[3];
    ss = red[4] + red[5] + red[6] + red[7];
    float mu  = s * (1.0f / D_MODEL);
    float var = ss * (1.0f / D_MODEL) - mu * mu;
    float inv = rsqrtf(var + 1e-5f);
    float4 wv = ((const float4*)w)[tid];
    float4 bv = ((const float4*)b)[tid];
    ushort4 o4;
    o4.x = f2bf((v.x - mu) * inv * wv.x + bv.x);
    o4.y = f2bf((v.y - mu) * inv * wv.y + bv.y);
    o4.z = f2bf((v.z - mu) * inv * wv.z + bv.z);
    o4.w = f2bf((v.w - mu) * inv * wv.w + bv.w);
    ((ushort4*)(xn + (size_t)row * D_MODEL))[tid] = o4;
}

// ---------------- bf16 MFMA GEMM: C[M,N] = A[M,K] * B[N,K]^T  (f32 out) -----------
// MODE 0: col<splitN -> C (f32); col>=splitN -> Zb (bf16, col-splitN), both ld=ldc
// MODE 2: C = acc + extra[row*ldc+col]   (residual)
template <int MODE>
__global__ __launch_bounds__(256) void gemm_mfma(
    const ushort* __restrict__ A, int lda,
    const ushort* __restrict__ B, int ldb,
    float* __restrict__ C, ushort* __restrict__ Zb, int ldc, int splitN,
    const float* __restrict__ extra, int K) {
    __shared__ ushort lds[2][2][128 * 32];
    int tid = threadIdx.x;
    int w = tid >> 6, lane = tid & 63;
    int bm = blockIdx.y * 128, bn = blockIdx.x * 128;
    int wr = w >> 1, wc = w & 1;

    int srow = tid >> 2, sseg = (tid & 3) << 3;
    const ushort* Abase = A + (size_t)(bm + srow) * lda + sseg;
    const ushort* Bbase = B + (size_t)(bn + srow) * ldb + sseg;
    int l0 = w * 512;

    int frow = lane & 15, fk = (lane >> 4) << 3;
    f32x4 acc[4][4] = {};

#define STAGE(buf, k0)                                                        \
    do {                                                                      \
        gld_lds16(Abase + (k0),                     &lds[buf][0][l0]);        \
        gld_lds16(Abase + (size_t)64 * lda + (k0),  &lds[buf][0][2048 + l0]); \
        gld_lds16(Bbase + (k0),                     &lds[buf][1][l0]);        \
        gld_lds16(Bbase + (size_t)64 * ldb + (k0),  &lds[buf][1][2048 + l0]); \
    } while (0)

    int nk = K >> 5;
    int cur = 0;
    STAGE(0, 0);
    __syncthreads();
    for (int kt = 0; kt < nk; ++kt) {
        if (kt + 1 < nk) STAGE(cur ^ 1, (kt + 1) << 5);
        bf16x8 a[4], b[4];
#pragma unroll
        for (int m = 0; m < 4; ++m)
            a[m] = *(const bf16x8*)&lds[cur][0][(wr * 64 + m * 16 + frow) * 32 + fk];
#pragma unroll
        for (int n = 0; n < 4; ++n)
            b[n] = *(const bf16x8*)&lds[cur][1][(wc * 64 + n * 16 + frow) * 32 + fk];
#pragma unroll
        for (int m = 0; m < 4; ++m)
#pragma unroll
            for (int n = 0; n < 4; ++n)
                acc[m][n] = __builtin_amdgcn_mfma_f32_16x16x32_bf16(a[m], b[n], acc[m][n], 0, 0, 0);
        __syncthreads();
        cur ^= 1;
    }
#undef STAGE

    int rbase = bm + wr * 64 + ((lane >> 4) << 2);
    int cbase = bn + wc * 64 + (lane & 15);
#pragma unroll
    for (int m = 0; m < 4; ++m) {
#pragma unroll
        for (int n = 0; n < 4; ++n) {
            int gc = cbase + n * 16;
#pragma unroll
            for (int j = 0; j < 4; ++j) {
                int gr = rbase + m * 16 + j;
                float v = acc[m][n][j];
                if (MODE == 0) {
                    if (gc < splitN) C[(size_t)gr * ldc + gc] = v;
                    else             Zb[(size_t)gr * ldc + (gc - splitN)] = f2bf(v);
                } else {
                    C[(size_t)gr * ldc + gc] = v + extra[(size_t)gr * ldc + gc];
                }
            }
        }
    }
}

// ---------------- Generic f32 tiled GEMM ----------------
#define BM 64
#define BN 64
#define BK 16
// MODE 1: C = softplus(acc + extra[col]); MODE 3: plain
template <int MODE>
__global__ __launch_bounds__(256) void gemm_tn(const float* __restrict__ A, int lda,
                                               const float* __restrict__ B, int ldb,
                                               float* __restrict__ C, int ldc,
                                               int M, int N, int K,
                                               const float* __restrict__ extra) {
    __shared__ float As[BK][BM];
    __shared__ float Bs[BK][BN];
    int bm = blockIdx.y * BM, bn = blockIdx.x * BN;
    int tid = threadIdx.x;
    int tx = tid & 15, ty = tid >> 4;
    int lrow = tid >> 2, lseg = (tid & 3) << 2;
    float acc[4][4] = {};

    for (int k0 = 0; k0 < K; k0 += BK) {
        float4 av = make_float4(0.f, 0.f, 0.f, 0.f);
        float4 bv = make_float4(0.f, 0.f, 0.f, 0.f);
        int agr = bm + lrow;
        if (agr < M) av = *(const float4*)(A + (size_t)agr * lda + k0 + lseg);
        int bgr = bn + lrow;
        if (bgr < N) bv = *(const float4*)(B + (size_t)bgr * ldb + k0 + lseg);
        __syncthreads();
        As[lseg + 0][lrow] = av.x; As[lseg + 1][lrow] = av.y;
        As[lseg + 2][lrow] = av.z; As[lseg + 3][lrow] = av.w;
        Bs[lseg + 0][lrow] = bv.x; Bs[lseg + 1][lrow] = bv.y;
        Bs[lseg + 2][lrow] = bv.z; Bs[lseg + 3][lrow] = bv.w;
        __syncthreads();
#pragma unroll
        for (int k = 0; k < BK; ++k) {
            float4 a4 = *(const float4*)&As[k][ty << 2];
            float4 b4 = *(const float4*)&Bs[k][tx << 2];
            float ar[4] = {a4.x, a4.y, a4.z, a4.w};
            float br[4] = {b4.x, b4.y, b4.z, b4.w};
#pragma unroll
            for (int i = 0; i < 4; ++i)
#pragma unroll
                for (int j = 0; j < 4; ++j) acc[i][j] += ar[i] * br[j];
        }
    }

#pragma unroll
    for (int i = 0; i < 4; ++i) {
        int gr = bm + (ty << 2) + i;
        if (gr >= M) continue;
#pragma unroll
        for (int j = 0; j < 4; ++j) {
            int gc = bn + (tx << 2) + j;
            if (gc >= N) continue;
            float v = acc[i][j];
            if (MODE == 1) {
                v += extra[gc];
                v = (v > 20.f) ? v : log1pf(expf(v));
                C[(size_t)gr * ldc + gc] = v;
            } else {
                C[(size_t)gr * ldc + gc] = v;
            }
        }
    }
}

// ---------------- GEMM B split-K: part[kc] = xc[:,kc*128:+128] @ x_proj^T ---------
__global__ __launch_bounds__(256) void gemm_b_split(const float* __restrict__ A,
                                                    const float* __restrict__ B,
                                                    float* __restrict__ part) {
    __shared__ float As[BK][BM];
    __shared__ float Bs[BK][BN];
    int bm = blockIdx.y * BM, bn = blockIdx.x * BN;
    int kc = blockIdx.z;
    int tid = threadIdx.x;
    int tx = tid & 15, ty = tid >> 4;
    int lrow = tid >> 2, lseg = (tid & 3) << 2;
    float acc[4][4] = {};

    int kbeg = kc * KCH;
    for (int k0 = kbeg; k0 < kbeg + KCH; k0 += BK) {
        float4 av = *(const float4*)(A + (size_t)(bm + lrow) * D_INNER + k0 + lseg);
        float4 bv = make_float4(0.f, 0.f, 0.f, 0.f);
        int bgr = bn + lrow;
        if (bgr < 96) bv = *(const float4*)(B + (size_t)bgr * D_INNER + k0 + lseg);
        __syncthreads();
        As[lseg + 0][lrow] = av.x; As[lseg + 1][lrow] = av.y;
        As[lseg + 2][lrow] = av.z; As[lseg + 3][lrow] = av.w;
        Bs[lseg + 0][lrow] = bv.x; Bs[lseg + 1][lrow] = bv.y;
        Bs[lseg + 2][lrow] = bv.z; Bs[lseg + 3][lrow] = bv.w;
        __syncthreads();
#pragma unroll
        for (int k = 0; k < BK; ++k) {
            float4 a4 = *(const float4*)&As[k][ty << 2];
            float4 b4 = *(const float4*)&Bs[k][tx << 2];
            float ar[4] = {a4.x, a4.y, a4.z, a4.w};
            float br[4] = {b4.x, b4.y, b4.z, b4.w};
#pragma unroll
            for (int i = 0; i < 4; ++i)
#pragma unroll
                for (int j = 0; j < 4; ++j) acc[i][j] += ar[i] * br[j];
        }
    }

    float* po = part + (size_t)kc * (NROW * 96);
#pragma unroll
    for (int i = 0; i < 4; ++i) {
        int gr = bm + (ty << 2) + i;
#pragma unroll
        for (int j = 0; j < 4; ++j) {
            int gc = bn + (tx << 2) + j;
            if (gc < 96) po[(size_t)gr * 96 + gc] = acc[i][j];
        }
    }
}

__global__ __launch_bounds__(256) void gemm_b_reduce(const float* __restrict__ part,
                                                     float* __restrict__ dbl) {
    int i = blockIdx.x * 256 + threadIdx.x;  // 393216
    float s = 0.f;
#pragma unroll
    for (int kc = 0; kc < KSPLIT; ++kc)
        s += part[(size_t)kc * (NROW * 96) + i];
    dbl[i] = s;
}

// ---------------- causal depthwise conv1d (k=4, left pad 3) + SiLU ----------------
__global__ __launch_bounds__(256) void conv_silu(const float* __restrict__ xin,
                                                 const float* __restrict__ w,
                                                 const float* __restrict__ cb,
                                                 float* __restrict__ xc) {
    int idx = blockIdx.x * 256 + threadIdx.x;
    int d4 = idx & 511;
    int m  = idx >> 9;
    int l  = m & (SEQ - 1);
    int d  = d4 << 2;
    float4 w0 = ((const float4*)w)[d + 0];
    float4 w1 = ((const float4*)w)[d + 1];
    float4 w2 = ((const float4*)w)[d + 2];
    float4 w3 = ((const float4*)w)[d + 3];
    float wr0[4] = {w0.x, w0.y, w0.z, w0.w};
    float wr1[4] = {w1.x, w1.y, w1.z, w1.w};
    float wr2[4] = {w2.x, w2.y, w2.z, w2.w};
    float wr3[4] = {w3.x, w3.y, w3.z, w3.w};
    float ax = cb[d], ay = cb[d + 1], az = cb[d + 2], aw = cb[d + 3];
#pragma unroll
    for (int j = 0; j < 4; ++j) {
        if (l - 3 + j >= 0) {
            float4 xv = *(const float4*)(xin + (size_t)(m - 3 + j) * D_INNER + d);
            ax += wr0[j] * xv.x;
            ay += wr1[j] * xv.y;
            az += wr2[j] * xv.z;
            aw += wr3[j] * xv.w;
        }
    }
    float4 o;
    o.x = ax / (1.f + __expf(-ax));
    o.y = ay / (1.f + __expf(-ay));
    o.z = az / (1.f + __expf(-az));
    o.w = aw / (1.f + __expf(-aw));
    *(float4*)(xc + (size_t)m * D_INNER + d) = o;
}

// ---------------- chunked selective scan, 16 states per thread --------------------
#define EXP4(e, cj) \
    e.x = __expf(dt * cj.x); e.y = __expf(dt * cj.y); \
    e.z = __expf(dt * cj.z); e.w = __expf(dt * cj.w);
#define HUPD(hj, cj, Bv) { float4 e; EXP4(e, cj) \
    hj.x = e.x * hj.x + du * Bv.x; hj.y = e.y * hj.y + du * Bv.y; \
    hj.z = e.z * hj.z + du * Bv.z; hj.w = e.w * hj.w + du * Bv.w; }

__global__ __launch_bounds__(256) void scan_phase1(const float* __restrict__ delta,
                                                   const float* __restrict__ xc,
                                                   const float* __restrict__ dbl,
                                                   const float* __restrict__ A_log,
                                                   float* __restrict__ S,
                                                   float* __restrict__ sumdt) {
    int g = blockIdx.x * 256 + threadIdx.x;   // 262144
    int c = g & (NCH - 1);
    int k = g >> 12;
    int d = c & (D_INNER - 1);
    int b = c >> 11;
    const float4* al = (const float4*)(A_log + d * D_STATE);
    float4 c0 = al[0], c1 = al[1], c2 = al[2], c3 = al[3];
    c0.x = -__expf(c0.x); c0.y = -__expf(c0.y); c0.z = -__expf(c0.z); c0.w = -__expf(c0.w);
    c1.x = -__expf(c1.x); c1.y = -__expf(c1.y); c1.z = -__expf(c1.z); c1.w = -__expf(c1.w);
    c2.x = -__expf(c2.x); c2.y = -__expf(c2.y); c2.z = -__expf(c2.z); c2.w = -__expf(c2.w);
    c3.x = -__expf(c3.x); c3.y = -__expf(c3.y); c3.z = -__expf(c3.z); c3.w = -__expf(c3.w);

    size_t r0 = (size_t)b * SEQ + (size_t)k * CL;
    const float* pd = delta + r0 * D_INNER + d;
    const float* pu = xc    + r0 * D_INNER + d;
    const float4* pB = (const float4*)(dbl + r0 * 96 + DT_RANK);
    float4 h0 = {}, h1 = {}, h2 = {}, h3 = {};
    float sdt = 0.f;
    for (int t = 0; t < CL; ++t) {
        float dt = *pd, u = *pu;
        float4 B0 = pB[0], B1 = pB[1], B2 = pB[2], B3 = pB[3];
        float du = dt * u;
        sdt += dt;
        HUPD(h0, c0, B0) HUPD(h1, c1, B1) HUPD(h2, c2, B2) HUPD(h3, c3, B3)
        pd += D_INNER; pu += D_INNER; pB += 24;
    }
    float4* So = (float4*)(S + ((size_t)g << 4));
    So[0] = h0; So[1] = h1; So[2] = h2; So[3] = h3;
    sumdt[g] = sdt;
}

// phase2: combine chunk summaries serially; hin written in-place over S
__global__ __launch_bounds__(256) void scan_phase2(float* __restrict__ S,
                                                   const float* __restrict__ sumdt,
                                                   const float* __restrict__ A_log) {
    int g = blockIdx.x * 256 + threadIdx.x;  // 65536
    int n = g & 15;
    int c = g >> 4;
    int d = c & (D_INNER - 1);
    float cn = -__expf(A_log[d * D_STATE + n]);
    float h = 0.f;
#pragma unroll 8
    for (int k = 0; k < NC; ++k) {
        int kc = (k << 12) | c;
        float P = __expf(sumdt[kc] * cn);
        size_t o = ((size_t)kc << 4) + n;
        float s = S[o];
        S[o] = h;              // hin for chunk k
        h = P * h + s;
    }
}

__global__ __launch_bounds__(256) void scan_phase3(const float* __restrict__ delta,
                                                   const float* __restrict__ xc,
                                                   const float* __restrict__ dbl,
                                                   const ushort* __restrict__ zb,
                                                   const float* __restrict__ A_log,
                                                   const float* __restrict__ Dp,
                                                   const float* __restrict__ hin,
                                                   ushort* __restrict__ y) {
    int g = blockIdx.x * 256 + threadIdx.x;
    int c = g & (NCH - 1);
    int k = g >> 12;
    int d = c & (D_INNER - 1);
    int b = c >> 11;
    const float4* al = (const float4*)(A_log + d * D_STATE);
    float4 c0 = al[0], c1 = al[1], c2 = al[2], c3 = al[3];
    c0.x = -__expf(c0.x); c0.y = -__expf(c0.y); c0.z = -__expf(c0.z); c0.w = -__expf(c0.w);
    c1.x = -__expf(c1.x); c1.y = -__expf(c1.y); c1.z = -__expf(c1.z); c1.w = -__expf(c1.w);
    c2.x = -__expf(c2.x); c2.y = -__expf(c2.y); c2.z = -__expf(c2.z); c2.w = -__expf(c2.w);
    c3.x = -__expf(c3.x); c3.y = -__expf(c3.y); c3.z = -__expf(c3.z); c3.w = -__expf(c3.w);
    float Dv = Dp[d];
    const float4* hi = (const float4*)(hin + ((size_t)g << 4));
    float4 h0 = hi[0], h1 = hi[1], h2 = hi[2], h3 = hi[3];

    size_t r0 = (size_t)b * SEQ + (size_t)k * CL;
    const float* pd = delta + r0 * D_INNER + d;
    const float* pu = xc    + r0 * D_INNER + d;
    const ushort* pz = zb   + r0 * D_INNER + d;
    ushort* py = y          + r0 * D_INNER + d;
    const float4* pB = (const float4*)(dbl + r0 * 96 + DT_RANK);
    for (int t = 0; t < CL; ++t) {
        float dt = *pd, u = *pu;
        float4 B0 = pB[0], B1 = pB[1], B2 = pB[2], B3 = pB[3];
        float4 C0 = pB[4], C1 = pB[5], C2 = pB[6], C3 = pB[7];
        float du = dt * u;
        HUPD(h0, c0, B0) HUPD(h1, c1, B1) HUPD(h2, c2, B2) HUPD(h3, c3, B3)
        float acc = h0.x * C0.x + h0.y * C0.y + h0.z * C0.z + h0.w * C0.w
                  + h1.x * C1.x + h1.y * C1.y + h1.z * C1.z + h1.w * C1.w
                  + h2.x * C2.x + h2.y * C2.y + h2.z * C2.z + h2.w * C2.w
                  + h3.x * C3.x + h3.y * C3.y + h3.z * C3.z + h3.w * C3.w;
        float zv = bf2f(*pz);
        float sz = zv / (1.f + __expf(-zv));
        *py = f2bf((acc + u * Dv) * sz);
        pd += D_INNER; pu += D_INNER; pz += D_INNER; py += D_INNER; pB += 24;
    }
}

extern "C" void kernel_launch(void* const* d_in, const int* in_sizes, int n_in,
                              void* d_out, int out_size, void* d_ws, size_t ws_size,
                              hipStream_t stream) {
    const float* x       = (const float*)d_in[0];
    const float* ln_w    = (const float*)d_in[1];
    const float* ln_b    = (const float*)d_in[2];
    const float* in_proj = (const float*)d_in[3];
    const float* conv_w  = (const float*)d_in[4];
    const float* conv_b  = (const float*)d_in[5];
    const float* x_proj  = (const float*)d_in[6];
    const float* dt_w    = (const float*)d_in[7];
    const float* dt_b    = (const float*)d_in[8];
    const float* A_log   = (const float*)d_in[9];
    const float* Dp      = (const float*)d_in[10];
    const float* out_w   = (const float*)d_in[11];
    float* out = (float*)d_out;

    char* ws = (char*)d_ws;
    const size_t MB = 1024ull * 1024ull;
    // Layout / lifetimes:
    // [0,8)    xn_bf (LN -> GEMM A);   [0,16) Shin overlay (phase1..3)
    // [8,16)   w_in_bf (cvt -> GEMM A)
    // [16,48)  x_in f32 (GEMM A -> conv); then part [16,41) (split -> reduce);
    //          then y_bf [16,32) (ph3 -> GEMM D), w_out_bf [32,36) (cvt -> GEMM D),
    //          sumdt [36,37) (ph1 -> ph2)
    // [48,64)  zbuf_bf 16 MB (GEMM A -> phase3)
    // [64,96)  xc f32 (conv -> split, phase1/3)
    // [96,98)  dbl (reduce -> GEMM C, phase1/3)
    // [98,130) delta (GEMM C -> phase1/3)
    ushort* xn_bf    = (ushort*)(ws);
    ushort* w_in_bf  = (ushort*)(ws + 8 * MB);
    float*  Shin     = (float*)(ws);
    float*  x_in     = (float*)(ws + 16 * MB);
    float*  part     = (float*)(ws + 16 * MB);    // 25 MB: [16][4096][96] f32
    ushort* y_bf     = (ushort*)(ws + 16 * MB);
    ushort* w_out_bf = (ushort*)(ws + 32 * MB);
    float*  sumdt    = (float*)(ws + 36 * MB);
    ushort* zbuf_bf  = (ushort*)(ws + 48 * MB);
    float*  xc       = (float*)(ws + 64 * MB);
    float*  dbl      = (float*)(ws + 96 * MB);
    float*  delta    = (float*)(ws + 98 * MB);

    // 0. convert in_proj weights to bf16 (4096x1024)
    cvt_bf16<<<(2 * D_INNER * D_MODEL / 4) / 256, 256, 0, stream>>>(in_proj, w_in_bf);

    // 1. LayerNorm -> bf16
    ln_kernel<<<NROW, 256, 0, stream>>>(x, ln_w, ln_b, xn_bf);

    // 2. xz = xn @ in_proj^T  -> x_in (f32) | z (bf16)
    gemm_mfma<0><<<dim3(4096 / 128, NROW / 128), 256, 0, stream>>>(
        xn_bf, D_MODEL, w_in_bf, D_MODEL, x_in, zbuf_bf, D_INNER, D_INNER,
        nullptr, D_MODEL);

    // 3. causal depthwise conv + SiLU -> xc  (x_in dead after this)
    conv_silu<<<(NROW * (D_INNER / 4)) / 256, 256, 0, stream>>>(x_in, conv_w, conv_b, xc);

    // 4. dbl = xc @ x_proj^T  [4096,96] via split-K + reduce
    gemm_b_split<<<dim3(2, NROW / BM, KSPLIT), 256, 0, stream>>>(xc, x_proj, part);
    gemm_b_reduce<<<(NROW * 96) / 256, 256, 0, stream>>>(part, dbl);

    // 4b. convert out_proj weights to bf16 (part region dead after reduce)
    cvt_bf16<<<(D_MODEL * D_INNER / 4) / 256, 256, 0, stream>>>(out_w, w_out_bf);

    // 5. delta = softplus(dt @ dt_proj^T + dt_b)   [4096, 2048]
    gemm_tn<1><<<dim3(D_INNER / BN, NROW / BM), 256, 0, stream>>>(
        dbl, 96, dt_w, DT_RANK, delta, D_INNER, NROW, D_INNER, DT_RANK, dt_b);

    // 6. chunked selective scan (16 states/thread; skip & gate fused in phase 3)
    scan_phase1<<<(NCH * NC) / 256, 256, 0, stream>>>(
        delta, xc, dbl, A_log, Shin, sumdt);
    scan_phase2<<<(NCH * D_STATE) / 256, 256, 0, stream>>>(Shin, sumdt, A_log);
    scan_phase3<<<(NCH * NC) / 256, 256, 0, stream>>>(
        delta, xc, dbl, zbuf_bf, A_log, Dp, Shin, y_bf);

    // 7. out = y @ out_proj^T + x   (bf16 MFMA, residual epilogue)
    gemm_mfma<2><<<dim3(D_MODEL / 128, NROW / 128), 256, 0, stream>>>(
        y_bf, D_INNER, w_out_bf, D_INNER, out, nullptr, D_MODEL, 0,
        x, D_INNER);
}